// Round 12
// baseline (236.796 us; speedup 1.0000x reference)
//
#include <hip/hip_runtime.h>
#include <hip/hip_bf16.h>

#define B_ 4
#define S_ 1024
#define E_ 1280
#define H_ 16
#define D_ 80
#define M_ (B_*S_)   // 4096

typedef __hip_bfloat16 bf16;
using bf16x8 = __attribute__((ext_vector_type(8))) short;  // 8 bf16 = 4 VGPRs
using f32x4  = __attribute__((ext_vector_type(4))) float;  // MFMA C/D frag

__device__ __forceinline__ float b2f(bf16 x){ return __bfloat162float(x); }
__device__ __forceinline__ bf16  f2b(float x){ return __float2bfloat16(x); }

__device__ __forceinline__ void gload_lds16(const void* g, void* l) {
    __builtin_amdgcn_global_load_lds(
        (const __attribute__((address_space(1))) unsigned int*)g,
        (__attribute__((address_space(3))) unsigned int*)l, 16, 0, 0);
}

// 8-phase sync helpers (rule #18: sched_barrier(0) after inline waitcnt)
__device__ __forceinline__ void ph_begin() {
    __builtin_amdgcn_s_barrier();
    asm volatile("s_waitcnt lgkmcnt(0)" ::: "memory");
    __builtin_amdgcn_sched_barrier(0);
    __builtin_amdgcn_s_setprio(1);
}
__device__ __forceinline__ void ph_end() {
    __builtin_amdgcn_s_setprio(0);
    __builtin_amdgcn_sched_barrier(0);
    __builtin_amdgcn_s_barrier();
}
__device__ __forceinline__ void ph_end_vm6() {
    __builtin_amdgcn_s_setprio(0);
    __builtin_amdgcn_sched_barrier(0);
    asm volatile("s_waitcnt vmcnt(6)" ::: "memory");
    __builtin_amdgcn_s_barrier();
}
__device__ __forceinline__ void ph_end_vm0() {
    __builtin_amdgcn_s_setprio(0);
    __builtin_amdgcn_sched_barrier(0);
    asm volatile("s_waitcnt vmcnt(0)" ::: "memory");
    __builtin_amdgcn_s_barrier();
}

// ============================================================================
// fp32 -> bf16 conversion, 8 elems/thread. blockIdx.y selects segment.
// Segments 1 (wq) and 2 (wk): PAIR-INTERLEAVED rows (rope pairs adjacent).
// Segment 5: builds the fused transposed rope table cst[dcs][s][2] (f32):
//   cst[(dcs*1024+s)*2+0] = cos[s][dcs], +1 = sin[s][dcs]  (320 KB, L2-fit)
// so the qkv epilogue loads coefficients as contiguous float4s.
// ============================================================================
__global__ __launch_bounds__(256) void cvt_kernel(
    const float* __restrict__ s0_, const float* __restrict__ s1_,
    const float* __restrict__ s2_, const float* __restrict__ s3_,
    const float* __restrict__ s4_,
    const float* __restrict__ cosp, const float* __restrict__ sinp,
    bf16* __restrict__ d0, bf16* __restrict__ d1, bf16* __restrict__ d2,
    bf16* __restrict__ d3, bf16* __restrict__ d4, float* __restrict__ cst,
    int n0, int n1)
{
    if (blockIdx.y == 5) {
        int i = (blockIdx.x * 256 + threadIdx.x) * 8;
        if (i >= 40 * S_ * 2) return;
        const int dcs = i >> 11;            // / 2048
        const int s0v = (i & 2047) >> 1;    // / 2 (multiple of 4)
        float4 w0, w1;
        w0.x = cosp[(s0v    )*D_ + dcs]; w0.y = sinp[(s0v    )*D_ + dcs];
        w0.z = cosp[(s0v + 1)*D_ + dcs]; w0.w = sinp[(s0v + 1)*D_ + dcs];
        w1.x = cosp[(s0v + 2)*D_ + dcs]; w1.y = sinp[(s0v + 2)*D_ + dcs];
        w1.z = cosp[(s0v + 3)*D_ + dcs]; w1.w = sinp[(s0v + 3)*D_ + dcs];
        *(float4*)&cst[i]     = w0;
        *(float4*)&cst[i + 4] = w1;
        return;
    }
    const float* s; bf16* d; int n;
    bool perm = false;
    switch (blockIdx.y) {
        case 0: s = s0_; d = d0; n = n0; break;
        case 1: s = s1_; d = d1; n = n1; perm = true; break;
        case 2: s = s2_; d = d2; n = n1; perm = true; break;
        case 3: s = s3_; d = d3; n = n1; break;
        default: s = s4_; d = d4; n = n1; break;
    }
    int i = (blockIdx.x * 256 + threadIdx.x) * 8;
    if (i >= n) return;
    const float* src = s + i;
    if (perm) {
        const int row = i / E_;           // dest row (permuted position)
        const int col = i - row * E_;
        const int e   = row % 80;
        const int nr  = (row - e) + ((e & 1) ? 40 + (e >> 1) : (e >> 1));
        src = s + (size_t)nr * E_ + col;
    }
    float4 a = *(const float4*)(src);
    float4 b = *(const float4*)(src + 4);
    bf16 t[8];
    t[0]=f2b(a.x); t[1]=f2b(a.y); t[2]=f2b(a.z); t[3]=f2b(a.w);
    t[4]=f2b(b.x); t[5]=f2b(b.y); t[6]=f2b(b.z); t[7]=f2b(b.w);
    *(uint4*)(d + i) = *(const uint4*)t;
}

// ============================================================================
// QKV projection: 256x256 8-phase MFMA GEMM (T2+T3+T4+T5), identity block
// mapping, + FUSED ROPE in the epilogue for mats 0,1 (q,k):
//  - wq/wk rows pre-permuted pair-interleaved -> rope partner = lane^1
//    -> pv = __shfl_xor(v,1) (DPP, no LDS).
//  - coefficients from cst[dcs][s][2]: s runs consecutively with r ->
//    two float4 loads per (nt,mt) (r12: was 8 scalar loads per (nt,mt,r)).
//  - even p: v*c - pv*s ; odd p: v*c + pv*s ; Q additionally scaled 1/sqrt(80).
//  - bias fetched through the inverse permutation.
// mat 2 (V): unchanged transposed-VT epilogue.
// ============================================================================
__global__ __launch_bounds__(512, 2) void qkv_gemm_8ph(
    const bf16* __restrict__ A,
    const bf16* __restrict__ W0, const bf16* __restrict__ W1, const bf16* __restrict__ W2,
    const float* __restrict__ b0, const float* __restrict__ b1, const float* __restrict__ b2,
    const float* __restrict__ cst,
    bf16* __restrict__ Cq, bf16* __restrict__ Ck, bf16* __restrict__ Cv)
{
    constexpr int K = 1280;
    constexpr int NITER = K / 128;   // 10 iterations, 2 K-tiles each

    __shared__ __align__(16) bf16 Asm[2][2][128*64];   // [buf][half][row*64+col]
    __shared__ __align__(16) bf16 Bsm[2][2][128*64];

    const int bm  = blockIdx.x * 256;
    const int ny  = blockIdx.y;            // 0..14
    const int mat = ny / 5;
    const int bn  = (ny % 5) * 256;        // col base within matrix
    const bf16*  W    = (mat == 0) ? W0 : (mat == 1) ? W1 : W2;
    const float* bias = (mat == 0) ? b0 : (mat == 1) ? b1 : b2;

    const int tid  = threadIdx.x;
    const int lane = tid & 63, wv = tid >> 6;
    const int wm = wv >> 2, wn = wv & 3;        // wave tile: rows wm*128, cols wn*64
    const int quad = lane >> 4, l15 = lane & 15;

    auto stageA = [&](int j_, int half) {
        #pragma unroll
        for (int i = 0; i < 2; i++) {
            const int c   = tid + i*512;
            const int row = c >> 3;
            const int g   = (c & 7) ^ (row & 7);
            gload_lds16(A + (size_t)(bm + half*128 + row) * K + j_*64 + g*8,
                        &Asm[j_ & 1][half][(wv*64 + i*512) * 8]);
        }
    };
    auto stageB = [&](int j_, int half) {
        #pragma unroll
        for (int i = 0; i < 2; i++) {
            const int c   = tid + i*512;
            const int row = c >> 3;
            const int g   = (c & 7) ^ (row & 7);
            gload_lds16(W + (size_t)(bn + half*128 + row) * K + j_*64 + g*8,
                        &Bsm[j_ & 1][half][(wv*64 + i*512) * 8]);
        }
    };
    auto lda = [&](int bf, int mt, int ks) -> bf16x8 {
        const int r = mt*16 + l15;
        return *(const bf16x8*)&Asm[bf][wm][r*64 + (((quad + ks*4) ^ (r & 7)) << 3)];
    };
    auto ldb = [&](int bf, int nt, int ks) -> bf16x8 {
        const int r = (wn & 1)*64 + nt*16 + l15;
        return *(const bf16x8*)&Bsm[bf][wn >> 1][r*64 + (((quad + ks*4) ^ (r & 7)) << 3)];
    };

    f32x4 acc[8][4] = {};
    bf16x8 a[4][2], bA[2][2], bB[2][2];

#define MFMA_Q(MT0, NT0, BB_) do { \
    _Pragma("unroll") for (int mt_ = 0; mt_ < 4; mt_++) \
    _Pragma("unroll") for (int nt_ = 0; nt_ < 2; nt_++) \
    _Pragma("unroll") for (int ks_ = 0; ks_ < 2; ks_++) \
        acc[(MT0)+mt_][(NT0)+nt_] = __builtin_amdgcn_mfma_f32_16x16x32_bf16( \
            a[mt_][ks_], BB_[nt_][ks_], acc[(MT0)+mt_][(NT0)+nt_], 0, 0, 0); \
} while (0)

    stageA(0, 0); stageA(0, 1); stageB(0, 0); stageB(0, 1);
    stageA(1, 0); stageA(1, 1); stageB(1, 0); stageB(1, 1);
    __syncthreads();

    for (int t = 0; t < NITER; t++) {
        const int  j  = 2*t;
        const bool pf = (t + 1 < NITER);

        #pragma unroll
        for (int mt = 0; mt < 4; mt++) { a[mt][0] = lda(0, mt, 0); a[mt][1] = lda(0, mt, 1); }
        #pragma unroll
        for (int nt = 0; nt < 2; nt++) { bA[nt][0] = ldb(0, nt, 0); bA[nt][1] = ldb(0, nt, 1); }
        stageA(j+1, 1);
        ph_begin(); MFMA_Q(0, 0, bA); ph_end();

        #pragma unroll
        for (int nt = 0; nt < 2; nt++) { bB[nt][0] = ldb(0, 2+nt, 0); bB[nt][1] = ldb(0, 2+nt, 1); }
        ph_begin(); MFMA_Q(0, 2, bB); ph_end();

        #pragma unroll
        for (int mt = 0; mt < 4; mt++) { a[mt][0] = lda(0, 4+mt, 0); a[mt][1] = lda(0, 4+mt, 1); }
        if (pf) stageB(j+2, 0);
        ph_begin(); MFMA_Q(4, 0, bA); ph_end();

        if (pf) { stageB(j+2, 1); stageA(j+2, 0); }
        ph_begin(); MFMA_Q(4, 2, bB);
        if (pf) ph_end_vm6(); else ph_end_vm0();

        #pragma unroll
        for (int mt = 0; mt < 4; mt++) { a[mt][0] = lda(1, mt, 0); a[mt][1] = lda(1, mt, 1); }
        #pragma unroll
        for (int nt = 0; nt < 2; nt++) { bA[nt][0] = ldb(1, nt, 0); bA[nt][1] = ldb(1, nt, 1); }
        if (pf) stageA(j+2, 1);
        ph_begin(); MFMA_Q(0, 0, bA); ph_end();

        #pragma unroll
        for (int nt = 0; nt < 2; nt++) { bB[nt][0] = ldb(1, 2+nt, 0); bB[nt][1] = ldb(1, 2+nt, 1); }
        ph_begin(); MFMA_Q(0, 2, bB); ph_end();

        #pragma unroll
        for (int mt = 0; mt < 4; mt++) { a[mt][0] = lda(1, 4+mt, 0); a[mt][1] = lda(1, 4+mt, 1); }
        if (pf) stageB(j+3, 0);
        ph_begin(); MFMA_Q(4, 0, bA); ph_end();

        if (pf) { stageB(j+3, 1); stageA(j+3, 0); }
        ph_begin(); MFMA_Q(4, 2, bB); ph_end_vm6();
    }
#undef MFMA_Q

    if (mat < 2) {
        bf16* C = (mat == 0) ? Cq : Ck;
        const float mul = (mat == 0) ? 0.11180339887498949f : 1.0f;
        #pragma unroll
        for (int nt = 0; nt < 4; nt++) {
            const int p  = bn + wn*64 + nt*16 + l15;   // permuted output col
            const int e  = p % 80;
            const int nr = (p - e) + ((e & 1) ? 40 + (e >> 1) : (e >> 1));
            const float bv = bias[nr];                 // bias via inverse perm
            const int dcs  = e >> 1;                   // cos/sin index (0..39)
            const bool odd = (e & 1);
            #pragma unroll
            for (int mt = 0; mt < 8; mt++) {
                const int m0 = bm + wm*128 + mt*16 + quad*4;
                const int s0 = m0 & (S_ - 1);          // multiple of 4
                const float4 cs01 = *(const float4*)&cst[(dcs*S_ + s0)*2];
                const float4 cs23 = *(const float4*)&cst[(dcs*S_ + s0)*2 + 4];
                const float cc[4] = {cs01.x, cs01.z, cs23.x, cs23.z};
                const float ss[4] = {cs01.y, cs01.w, cs23.y, cs23.w};
                #pragma unroll
                for (int r = 0; r < 4; r++) {
                    const float v  = acc[mt][nt][r] + bv;
                    const float pv = __shfl_xor(v, 1, 64);   // rope partner
                    const float out = odd ? (v*cc[r] + pv*ss[r]) : (v*cc[r] - pv*ss[r]);
                    C[(size_t)(m0 + r) * E_ + p] = f2b(out * mul);
                }
            }
        }
    } else {
        #pragma unroll
        for (int nt = 0; nt < 4; nt++) {
            const int ncol = bn + wn*64 + nt*16 + l15;
            const float bv = bias[ncol];
            const int hh = ncol / 80, dd = ncol % 80;
            #pragma unroll
            for (int mt = 0; mt < 8; mt++) {
                const int m0  = bm + wm*128 + mt*16 + quad*4;
                const int btok = m0 >> 10;
                const int key  = m0 & 1023;
                union { bf16 h[4]; uint2 u; } t4;
                #pragma unroll
                for (int r = 0; r < 4; r++) t4.h[r] = f2b(acc[mt][nt][r] + bv);
                *(uint2*)&Cv[((size_t)(btok*H_ + hh)*D_ + dd)*S_ + key] = t4.u;
            }
        }
    }
}

// ============================================================================
// Output projection: m97-style 128x128 GEMM (unswapped, scalar-store
// epilogue). Unchanged from r10/r11.
// ============================================================================
__global__ __launch_bounds__(256) void oproj_gemm(
    const bf16* __restrict__ A, const bf16* __restrict__ W,
    const float* __restrict__ bias, float* __restrict__ C)
{
    const int K = E_, N = E_;
    const int bn = blockIdx.y * 128;
    const int bm = blockIdx.x * 128;

    __shared__ bf16 As[2][128][32];
    __shared__ bf16 Ws[2][128][32];

    const int tid  = threadIdx.x;
    const int lane = tid & 63;
    const int wv   = tid >> 6;
    const int wm   = (wv & 1) * 64;
    const int wn   = (wv >> 1) * 64;
    const int srow = wv * 16 + (lane >> 2);
    const int scol = (lane & 3) * 8;

    f32x4 acc[4][4] = {};

    for (int k0 = 0; k0 < K; k0 += 64) {
        __syncthreads();
        #pragma unroll
        for (int p = 0; p < 2; p++) {
            const int kc = k0 + p*32 + scol;
            gload_lds16(A + (size_t)(bm + srow)      * K + kc, &As[p][wv*16][0]);
            gload_lds16(A + (size_t)(bm + 64 + srow) * K + kc, &As[p][64 + wv*16][0]);
            gload_lds16(W + (size_t)(bn + srow)      * K + kc, &Ws[p][wv*16][0]);
            gload_lds16(W + (size_t)(bn + 64 + srow) * K + kc, &Ws[p][64 + wv*16][0]);
        }
        __syncthreads();

        const int fr = lane & 15;
        const int kq = (lane >> 4) * 8;
        #pragma unroll
        for (int p = 0; p < 2; p++) {
            bf16x8 af[4], wf[4];
            #pragma unroll
            for (int t = 0; t < 4; t++) {
                af[t] = *(const bf16x8*)&As[p][wm + t*16 + fr][kq];
                wf[t] = *(const bf16x8*)&Ws[p][wn + t*16 + fr][kq];
            }
            #pragma unroll
            for (int mt = 0; mt < 4; mt++)
                #pragma unroll
                for (int nt = 0; nt < 4; nt++)
                    acc[mt][nt] = __builtin_amdgcn_mfma_f32_16x16x32_bf16(
                        af[mt], wf[nt], acc[mt][nt], 0, 0, 0);
        }
    }

    const int col_l = lane & 15;
    const int row_l = (lane >> 4) * 4;
    #pragma unroll
    for (int nt = 0; nt < 4; nt++) {
        const int n = bn + wn + nt*16 + col_l;
        const float bv = bias[n];
        #pragma unroll
        for (int mt = 0; mt < 4; mt++) {
            #pragma unroll
            for (int r = 0; r < 4; r++) {
                const int m = bm + wm + mt*16 + row_l + r;
                C[(size_t)m * N + n] = acc[mt][nt][r] + bv;
            }
        }
    }
}

// ============================================================================
// MFMA flash attention v11d — unchanged from r10/r11. q/k arrive pre-roped,
// pre-scaled, in pair-interleaved D layout (QK^T permutation-invariant).
// ============================================================================
__global__ __launch_bounds__(512, 2) void attn_mfma(
    const bf16* __restrict__ q, const bf16* __restrict__ k, const bf16* __restrict__ vt,
    const int* __restrict__ cu, bf16* __restrict__ o)
{
    __shared__ __align__(16) bf16 Ks[2][64*80];    // 2 x 10240 B, swizzled
    __shared__ __align__(16) bf16 VTs[2][80*64];   // 2 x 10240 B, swizzled
    __shared__ __align__(16) bf16 PTq[8][16*72];   // per-wave P [query][key]

    const int n  = blockIdx.x;                 // 512 blocks
    const int g  = ((n >> 6) << 3) | (n & 7);  // (b,h): XCD = n&7 = h&7
    const int qs = (n >> 3) & 7;               // q-supertile 0..7 (128 rows)
    const int b  = g >> 4;
    const int h  = g & 15;

    const int tid  = threadIdx.x;
    const int lane = tid & 63, wv = tid >> 6;  // wv 0..7
    const int quad = lane >> 4, l15 = lane & 15;
    const int q0   = qs * 128;
    const int len  = cu[b + 1] - cu[b];

    const bool uniformq = (q0 >= len);
    const bool fast     = !uniformq && ((q0 + 128) <= len) && ((len & 63) == 0);
    const int  ktiles   = uniformq ? 16 : (fast ? (len >> 6) : 16);
    const bool domask   = !uniformq && !fast;

    bf16* PT = &PTq[wv][0];

    // Q fragments (B-operand), rows q0 + wv*16 + l15.
    bf16x8 qf[3] = {};
    if (!uniformq) {
        const bf16* qrow = q + (size_t)(b*S_ + q0 + wv*16 + l15)*E_ + h*D_ + quad*8;
        qf[0] = *(const bf16x8*)(qrow);
        qf[1] = *(const bf16x8*)(qrow + 32);
        if (quad < 2) qf[2] = *(const bf16x8*)(qrow + 64);
    }

    float m_s = -1e30f, l_s = 0.f;   // per-lane scalars (query = l15)
    f32x4 o_acc[5] = {};

    bf16x8 pone;
    {
        const short one_s = (short)0x3F80;   // bf16 1.0
        #pragma unroll
        for (int i = 0; i < 8; i++) pone[i] = one_s;
    }

    const int u_  = l15 >> 2;
    const int s0r = quad ^ u_;            // K granule ks=0
    const int sv0 = quad ^ (l15 & 7);     // V granule ks=0

    auto stage = [&](int kt, int bf) {
        #pragma unroll
        for (int i = 0; i < 3; i++) {
            int c = tid + i * 512;
            if (c < 640) {
                if (!uniformq) {
                    int row = c / 10, s5 = c - row * 10;
                    int uu = (row >> 2) & 3;
                    int sg = (s5 < 8) ? (s5 ^ uu) : (8 + ((s5 ^ uu) & 1));
                    gload_lds16(k + (size_t)(b*S_ + kt*64 + row)*E_ + h*D_ + sg*8,
                                &Ks[bf][c*8]);
                }
            } else if (c < 1280) {
                int c2 = c - 640;
                int row = c2 >> 3, s5 = c2 & 7;
                int sg = s5 ^ (row & 7);
                gload_lds16(vt + ((size_t)(b*H_ + h)*D_ + row)*S_ + kt*64 + sg*8,
                            &VTs[bf][c2*8]);
            }
        }
    };

    stage(0, 0);
    __syncthreads();   // buf0 ready

    for (int kt = 0; kt < ktiles; kt++) {
        const int cur = kt & 1;
        if (kt + 1 < ktiles) stage(kt + 1, cur ^ 1);   // loads fly during compute

        bf16x8 pf0 = pone, pf1 = pone;
        if (!uniformq) {
            // ---- QK^T swapped: A=K, B=Q -> C[key=quad*4+r (+nt*16)][query=l15]
            f32x4 s4[4];
            #pragma unroll
            for (int nt = 0; nt < 4; nt++) {
                const bf16* kr = &Ks[cur][(nt*16 + l15) * 80];
                bf16x8 kf0 = *(const bf16x8*)(kr + s0r*8);
                bf16x8 kf1 = *(const bf16x8*)(kr + 32 + s0r*8);
                bf16x8 kf2 = {};
                if (quad < 2) kf2 = *(const bf16x8*)(kr + 64 + (s0r & 1)*8);
                f32x4 a0 = {};
                a0 = __builtin_amdgcn_mfma_f32_16x16x32_bf16(kf0, qf[0], a0, 0, 0, 0);
                a0 = __builtin_amdgcn_mfma_f32_16x16x32_bf16(kf1, qf[1], a0, 0, 0, 0);
                a0 = __builtin_amdgcn_mfma_f32_16x16x32_bf16(kf2, qf[2], a0, 0, 0, 0);
                s4[nt] = a0;
            }

            // ---- masking (lane owns query l15; keys nt*16+quad*4+r)
            float sv[4][4];
            if (!domask) {
                #pragma unroll
                for (int nt = 0; nt < 4; nt++)
                    #pragma unroll
                    for (int r = 0; r < 4; r++)
                        sv[nt][r] = s4[nt][r];
            } else {
                const bool vq = (q0 + wv*16 + l15) < len;
                #pragma unroll
                for (int nt = 0; nt < 4; nt++)
                    #pragma unroll
                    for (int r = 0; r < 4; r++) {
                        const bool vk = (kt*64 + nt*16 + quad*4 + r) < len;
                        sv[nt][r] = (vq && vk) ? s4[nt][r] : -1e9f;
                    }
            }

            // ---- online softmax with T13 defer-max (THR=8)
            float rm[4];
            #pragma unroll
            for (int nt = 0; nt < 4; nt++)
                rm[nt] = fmaxf(fmaxf(sv[nt][0], sv[nt][1]), fmaxf(sv[nt][2], sv[nt][3]));
            float sloc = fmaxf(fmaxf(rm[0], rm[1]), fmaxf(rm[2], rm[3]));
            sloc = fmaxf(sloc, __shfl_xor(sloc, 16, 64));
            sloc = fmaxf(sloc, __shfl_xor(sloc, 32, 64));
            const bool resc = !__all(sloc <= m_s + 8.0f);   // wave-uniform
            const float mnew = resc ? fmaxf(m_s, sloc) : m_s;
            float p[4][4], lsum = 0.f;
            #pragma unroll
            for (int nt = 0; nt < 4; nt++)
                #pragma unroll
                for (int r = 0; r < 4; r++) {
                    p[nt][r] = __expf(sv[nt][r] - mnew);
                    lsum += p[nt][r];
                }
            lsum += __shfl_xor(lsum, 16, 64);
            lsum += __shfl_xor(lsum, 32, 64);
            if (resc) {
                const float alpha = __expf(m_s - mnew);
                l_s = l_s * alpha + lsum;
                m_s = mnew;
                #pragma unroll
                for (int dt = 0; dt < 5; dt++)
                    #pragma unroll
                    for (int r = 0; r < 4; r++)
                        o_acc[dt][r] *= alpha;
            } else {
                l_s += lsum;
            }

            // ---- P -> PT[query][key] (granule-swizzled, stride 72)
            #pragma unroll
            for (int nt = 0; nt < 4; nt++) {
                union { bf16 hh[4]; uint2 u; } w;
                #pragma unroll
                for (int r = 0; r < 4; r++) w.hh[r] = f2b(p[nt][r]);
                const int gw = (2*nt + (quad >> 1)) ^ (l15 & 7);
                *(uint2*)&PT[l15*72 + gw*8 + (quad & 1)*4] = w.u;
            }
            // ---- P-frags (same-wave RAW via lgkmcnt)
            pf0 = *(const bf16x8*)&PT[l15*72 + ((quad    ) ^ (l15 & 7))*8];
            pf1 = *(const bf16x8*)&PT[l15*72 + ((quad + 4) ^ (l15 & 7))*8];
        }

        // ---- PV: A=Vfrag, B=Pfrag -> O[d=quad*4+r (+dt*16)][query=l15]
        #pragma unroll
        for (int dt = 0; dt < 5; dt++) {
            const bf16* vr = &VTs[cur][(dt*16 + l15) * 64];
            bf16x8 vf0 = *(const bf16x8*)(vr + sv0*8);
            bf16x8 vf1 = *(const bf16x8*)(vr + (sv0 ^ 4)*8);
            o_acc[dt] = __builtin_amdgcn_mfma_f32_16x16x32_bf16(vf0, pf0, o_acc[dt], 0, 0, 0);
            o_acc[dt] = __builtin_amdgcn_mfma_f32_16x16x32_bf16(vf1, pf1, o_acc[dt], 0, 0, 0);
        }
        __syncthreads();   // reads of buf[cur] done; buf[cur^1] loads drained
    }

    // ---- epilogue: lane = query l15; d = dt*16 + quad*4 + r
    const float inv = uniformq ? (1.0f / 1024.0f) : (1.0f / l_s);
    const size_t row_g = (size_t)(b*S_ + q0 + wv*16 + l15);
    #pragma unroll
    for (int dt = 0; dt < 5; dt++) {
        union { bf16 hh[4]; uint2 u; } t4;
        #pragma unroll
        for (int r = 0; r < 4; r++) t4.hh[r] = f2b(o_acc[dt][r] * inv);
        *(uint2*)&o[row_g*E_ + h*D_ + dt*16 + quad*4] = t4.u;
    }
}

extern "C" void kernel_launch(void* const* d_in, const int* in_sizes, int n_in,
                              void* d_out, int out_size, void* d_ws, size_t ws_size,
                              hipStream_t stream)
{
    const float* x    = (const float*)d_in[0];
    const int*   cu   = (const int*)  d_in[1];
    const float* cosp = (const float*)d_in[2];
    const float* sinp = (const float*)d_in[3];
    const float* wq   = (const float*)d_in[4];
    const float* bq   = (const float*)d_in[5];
    const float* wk   = (const float*)d_in[6];
    const float* bk   = (const float*)d_in[7];
    const float* wv   = (const float*)d_in[8];
    const float* bv   = (const float*)d_in[9];
    const float* wo   = (const float*)d_in[10];
    const float* bo   = (const float*)d_in[11];
    float* out = (float*)d_out;

    bf16* q   = (bf16*)d_ws;
    bf16* kk  = q   + (size_t)M_ * E_;
    bf16* vt  = kk  + (size_t)M_ * E_;   // transposed V: [B][H][D][S]
    bf16* ao  = vt  + (size_t)M_ * E_;
    bf16* xb  = ao  + (size_t)M_ * E_;
    bf16* wqb = xb  + (size_t)M_ * E_;
    bf16* wkb = wqb + (size_t)E_ * E_;
    bf16* wvb = wkb + (size_t)E_ * E_;
    bf16* wob = wvb + (size_t)E_ * E_;
    float* cst = (float*)(wob + (size_t)E_ * E_);   // 40*1024*2 f32 = 320 KB

    // 0) convert x + 4 weight matrices to bf16 (wq/wk pair-interleaved),
    //    + build the fused transposed rope table cst (slice y=5)
    cvt_kernel<<<dim3(2560, 6), 256, 0, stream>>>(
        x, wq, wk, wv, wo, cosp, sinp, xb, wqb, wkb, wvb, wob, cst, M_*E_, E_*E_);

    // 1) QKV projection with FUSED RoPE (q pre-scaled), vectorized cs loads.
    qkv_gemm_8ph<<<dim3(M_/256, 15), 512, 0, stream>>>(
        xb, wqb, wkb, wvb, bq, bk, bv, cst, q, kk, vt);

    // 2) MFMA flash attention v11d
    attn_mfma<<<512, 512, 0, stream>>>(q, kk, vt, cu, ao);

    // 3) output projection (m97 GEMM, fp32 out, bias fused)
    oproj_gemm<<<dim3(M_/128, E_/128), 256, 0, stream>>>(ao, wob, bo, out);
}

// Round 13
// 236.749 us; speedup vs baseline: 1.0002x; 1.0002x over previous
//
#include <hip/hip_runtime.h>
#include <hip/hip_bf16.h>

#define B_ 4
#define S_ 1024
#define E_ 1280
#define H_ 16
#define D_ 80
#define M_ (B_*S_)   // 4096

typedef __hip_bfloat16 bf16;
using bf16x8 = __attribute__((ext_vector_type(8))) short;  // 8 bf16 = 4 VGPRs
using f32x4  = __attribute__((ext_vector_type(4))) float;  // MFMA C/D frag

__device__ __forceinline__ float b2f(bf16 x){ return __bfloat162float(x); }
__device__ __forceinline__ bf16  f2b(float x){ return __float2bfloat16(x); }

__device__ __forceinline__ void gload_lds16(const void* g, void* l) {
    __builtin_amdgcn_global_load_lds(
        (const __attribute__((address_space(1))) unsigned int*)g,
        (__attribute__((address_space(3))) unsigned int*)l, 16, 0, 0);
}

// 8-phase sync helpers (rule #18: sched_barrier(0) after inline waitcnt)
__device__ __forceinline__ void ph_begin() {
    __builtin_amdgcn_s_barrier();
    asm volatile("s_waitcnt lgkmcnt(0)" ::: "memory");
    __builtin_amdgcn_sched_barrier(0);
    __builtin_amdgcn_s_setprio(1);
}
__device__ __forceinline__ void ph_end() {
    __builtin_amdgcn_s_setprio(0);
    __builtin_amdgcn_sched_barrier(0);
    __builtin_amdgcn_s_barrier();
}
__device__ __forceinline__ void ph_end_vm6() {
    __builtin_amdgcn_s_setprio(0);
    __builtin_amdgcn_sched_barrier(0);
    asm volatile("s_waitcnt vmcnt(6)" ::: "memory");
    __builtin_amdgcn_s_barrier();
}
__device__ __forceinline__ void ph_end_vm0() {
    __builtin_amdgcn_s_setprio(0);
    __builtin_amdgcn_sched_barrier(0);
    asm volatile("s_waitcnt vmcnt(0)" ::: "memory");
    __builtin_amdgcn_s_barrier();
}

// ============================================================================
// fp32 -> bf16 conversion, 8 elems/thread. blockIdx.y selects segment.
// Segments 1 (wq) and 2 (wk): PAIR-INTERLEAVED rows (rope pairs adjacent).
// Segment 5: builds the fused transposed rope table cst[dcs][s][2] (f32).
// ============================================================================
__global__ __launch_bounds__(256) void cvt_kernel(
    const float* __restrict__ s0_, const float* __restrict__ s1_,
    const float* __restrict__ s2_, const float* __restrict__ s3_,
    const float* __restrict__ s4_,
    const float* __restrict__ cosp, const float* __restrict__ sinp,
    bf16* __restrict__ d0, bf16* __restrict__ d1, bf16* __restrict__ d2,
    bf16* __restrict__ d3, bf16* __restrict__ d4, float* __restrict__ cst,
    int n0, int n1)
{
    if (blockIdx.y == 5) {
        int i = (blockIdx.x * 256 + threadIdx.x) * 8;
        if (i >= 40 * S_ * 2) return;
        const int dcs = i >> 11;            // / 2048
        const int s0v = (i & 2047) >> 1;    // / 2 (multiple of 4)
        float4 w0, w1;
        w0.x = cosp[(s0v    )*D_ + dcs]; w0.y = sinp[(s0v    )*D_ + dcs];
        w0.z = cosp[(s0v + 1)*D_ + dcs]; w0.w = sinp[(s0v + 1)*D_ + dcs];
        w1.x = cosp[(s0v + 2)*D_ + dcs]; w1.y = sinp[(s0v + 2)*D_ + dcs];
        w1.z = cosp[(s0v + 3)*D_ + dcs]; w1.w = sinp[(s0v + 3)*D_ + dcs];
        *(float4*)&cst[i]     = w0;
        *(float4*)&cst[i + 4] = w1;
        return;
    }
    const float* s; bf16* d; int n;
    bool perm = false;
    switch (blockIdx.y) {
        case 0: s = s0_; d = d0; n = n0; break;
        case 1: s = s1_; d = d1; n = n1; perm = true; break;
        case 2: s = s2_; d = d2; n = n1; perm = true; break;
        case 3: s = s3_; d = d3; n = n1; break;
        default: s = s4_; d = d4; n = n1; break;
    }
    int i = (blockIdx.x * 256 + threadIdx.x) * 8;
    if (i >= n) return;
    const float* src = s + i;
    if (perm) {
        const int row = i / E_;           // dest row (permuted position)
        const int col = i - row * E_;
        const int e   = row % 80;
        const int nr  = (row - e) + ((e & 1) ? 40 + (e >> 1) : (e >> 1));
        src = s + (size_t)nr * E_ + col;
    }
    float4 a = *(const float4*)(src);
    float4 b = *(const float4*)(src + 4);
    bf16 t[8];
    t[0]=f2b(a.x); t[1]=f2b(a.y); t[2]=f2b(a.z); t[3]=f2b(a.w);
    t[4]=f2b(b.x); t[5]=f2b(b.y); t[6]=f2b(b.z); t[7]=f2b(b.w);
    *(uint4*)(d + i) = *(const uint4*)t;
}

// ============================================================================
// QKV projection: 256x256 8-phase MFMA GEMM (T2+T3+T4+T5), identity block
// mapping, + FUSED ROPE in the epilogue for mats 0,1 (q,k).
// r13: __launch_bounds__(512, 1) — cap 256 VGPR (empirical formula:
// cap = 131072/(block*arg2); the old (512,2) capped at 128, which the main
// loop exactly fills (acc[8][4] = 128 f32) -> the r11 rope epilogue SPILLED
// (signature: +24.6 MB WRITE with FETCH flat — spill stores drain L2->HBM,
// reloads hit L2). LDS (128 KB) limits to 1 block/CU regardless, so the
// higher cap costs no occupancy.
// ============================================================================
__global__ __launch_bounds__(512, 1) void qkv_gemm_8ph(
    const bf16* __restrict__ A,
    const bf16* __restrict__ W0, const bf16* __restrict__ W1, const bf16* __restrict__ W2,
    const float* __restrict__ b0, const float* __restrict__ b1, const float* __restrict__ b2,
    const float* __restrict__ cst,
    bf16* __restrict__ Cq, bf16* __restrict__ Ck, bf16* __restrict__ Cv)
{
    constexpr int K = 1280;
    constexpr int NITER = K / 128;   // 10 iterations, 2 K-tiles each

    __shared__ __align__(16) bf16 Asm[2][2][128*64];   // [buf][half][row*64+col]
    __shared__ __align__(16) bf16 Bsm[2][2][128*64];

    const int bm  = blockIdx.x * 256;
    const int ny  = blockIdx.y;            // 0..14
    const int mat = ny / 5;
    const int bn  = (ny % 5) * 256;        // col base within matrix
    const bf16*  W    = (mat == 0) ? W0 : (mat == 1) ? W1 : W2;
    const float* bias = (mat == 0) ? b0 : (mat == 1) ? b1 : b2;

    const int tid  = threadIdx.x;
    const int lane = tid & 63, wv = tid >> 6;
    const int wm = wv >> 2, wn = wv & 3;        // wave tile: rows wm*128, cols wn*64
    const int quad = lane >> 4, l15 = lane & 15;

    auto stageA = [&](int j_, int half) {
        #pragma unroll
        for (int i = 0; i < 2; i++) {
            const int c   = tid + i*512;
            const int row = c >> 3;
            const int g   = (c & 7) ^ (row & 7);
            gload_lds16(A + (size_t)(bm + half*128 + row) * K + j_*64 + g*8,
                        &Asm[j_ & 1][half][(wv*64 + i*512) * 8]);
        }
    };
    auto stageB = [&](int j_, int half) {
        #pragma unroll
        for (int i = 0; i < 2; i++) {
            const int c   = tid + i*512;
            const int row = c >> 3;
            const int g   = (c & 7) ^ (row & 7);
            gload_lds16(W + (size_t)(bn + half*128 + row) * K + j_*64 + g*8,
                        &Bsm[j_ & 1][half][(wv*64 + i*512) * 8]);
        }
    };
    auto lda = [&](int bf, int mt, int ks) -> bf16x8 {
        const int r = mt*16 + l15;
        return *(const bf16x8*)&Asm[bf][wm][r*64 + (((quad + ks*4) ^ (r & 7)) << 3)];
    };
    auto ldb = [&](int bf, int nt, int ks) -> bf16x8 {
        const int r = (wn & 1)*64 + nt*16 + l15;
        return *(const bf16x8*)&Bsm[bf][wn >> 1][r*64 + (((quad + ks*4) ^ (r & 7)) << 3)];
    };

    f32x4 acc[8][4] = {};
    bf16x8 a[4][2], bA[2][2], bB[2][2];

#define MFMA_Q(MT0, NT0, BB_) do { \
    _Pragma("unroll") for (int mt_ = 0; mt_ < 4; mt_++) \
    _Pragma("unroll") for (int nt_ = 0; nt_ < 2; nt_++) \
    _Pragma("unroll") for (int ks_ = 0; ks_ < 2; ks_++) \
        acc[(MT0)+mt_][(NT0)+nt_] = __builtin_amdgcn_mfma_f32_16x16x32_bf16( \
            a[mt_][ks_], BB_[nt_][ks_], acc[(MT0)+mt_][(NT0)+nt_], 0, 0, 0); \
} while (0)

    stageA(0, 0); stageA(0, 1); stageB(0, 0); stageB(0, 1);
    stageA(1, 0); stageA(1, 1); stageB(1, 0); stageB(1, 1);
    __syncthreads();

    for (int t = 0; t < NITER; t++) {
        const int  j  = 2*t;
        const bool pf = (t + 1 < NITER);

        #pragma unroll
        for (int mt = 0; mt < 4; mt++) { a[mt][0] = lda(0, mt, 0); a[mt][1] = lda(0, mt, 1); }
        #pragma unroll
        for (int nt = 0; nt < 2; nt++) { bA[nt][0] = ldb(0, nt, 0); bA[nt][1] = ldb(0, nt, 1); }
        stageA(j+1, 1);
        ph_begin(); MFMA_Q(0, 0, bA); ph_end();

        #pragma unroll
        for (int nt = 0; nt < 2; nt++) { bB[nt][0] = ldb(0, 2+nt, 0); bB[nt][1] = ldb(0, 2+nt, 1); }
        ph_begin(); MFMA_Q(0, 2, bB); ph_end();

        #pragma unroll
        for (int mt = 0; mt < 4; mt++) { a[mt][0] = lda(0, 4+mt, 0); a[mt][1] = lda(0, 4+mt, 1); }
        if (pf) stageB(j+2, 0);
        ph_begin(); MFMA_Q(4, 0, bA); ph_end();

        if (pf) { stageB(j+2, 1); stageA(j+2, 0); }
        ph_begin(); MFMA_Q(4, 2, bB);
        if (pf) ph_end_vm6(); else ph_end_vm0();

        #pragma unroll
        for (int mt = 0; mt < 4; mt++) { a[mt][0] = lda(1, mt, 0); a[mt][1] = lda(1, mt, 1); }
        #pragma unroll
        for (int nt = 0; nt < 2; nt++) { bA[nt][0] = ldb(1, nt, 0); bA[nt][1] = ldb(1, nt, 1); }
        if (pf) stageA(j+2, 1);
        ph_begin(); MFMA_Q(0, 0, bA); ph_end();

        #pragma unroll
        for (int nt = 0; nt < 2; nt++) { bB[nt][0] = ldb(1, 2+nt, 0); bB[nt][1] = ldb(1, 2+nt, 1); }
        ph_begin(); MFMA_Q(0, 2, bB); ph_end();

        #pragma unroll
        for (int mt = 0; mt < 4; mt++) { a[mt][0] = lda(1, 4+mt, 0); a[mt][1] = lda(1, 4+mt, 1); }
        if (pf) stageB(j+3, 0);
        ph_begin(); MFMA_Q(4, 0, bA); ph_end();

        if (pf) { stageB(j+3, 1); stageA(j+3, 0); }
        ph_begin(); MFMA_Q(4, 2, bB); ph_end_vm6();
    }
#undef MFMA_Q

    if (mat < 2) {
        bf16* C = (mat == 0) ? Cq : Ck;
        const float mul = (mat == 0) ? 0.11180339887498949f : 1.0f;
        #pragma unroll
        for (int nt = 0; nt < 4; nt++) {
            const int p  = bn + wn*64 + nt*16 + l15;   // permuted output col
            const int e  = p % 80;
            const int nr = (p - e) + ((e & 1) ? 40 + (e >> 1) : (e >> 1));
            const float bv = bias[nr];                 // bias via inverse perm
            const int dcs  = e >> 1;                   // cos/sin index (0..39)
            const bool odd = (e & 1);
            #pragma unroll
            for (int mt = 0; mt < 8; mt++) {
                const int m0 = bm + wm*128 + mt*16 + quad*4;
                const int s0 = m0 & (S_ - 1);          // multiple of 4
                const float4 cs01 = *(const float4*)&cst[(dcs*S_ + s0)*2];
                const float4 cs23 = *(const float4*)&cst[(dcs*S_ + s0)*2 + 4];
                const float cc[4] = {cs01.x, cs01.z, cs23.x, cs23.z};
                const float ss[4] = {cs01.y, cs01.w, cs23.y, cs23.w};
                #pragma unroll
                for (int r = 0; r < 4; r++) {
                    const float v  = acc[mt][nt][r] + bv;
                    const float pv = __shfl_xor(v, 1, 64);   // rope partner
                    const float out = odd ? (v*cc[r] + pv*ss[r]) : (v*cc[r] - pv*ss[r]);
                    C[(size_t)(m0 + r) * E_ + p] = f2b(out * mul);
                }
            }
        }
    } else {
        #pragma unroll
        for (int nt = 0; nt < 4; nt++) {
            const int ncol = bn + wn*64 + nt*16 + l15;
            const float bv = bias[ncol];
            const int hh = ncol / 80, dd = ncol % 80;
            #pragma unroll
            for (int mt = 0; mt < 8; mt++) {
                const int m0  = bm + wm*128 + mt*16 + quad*4;
                const int btok = m0 >> 10;
                const int key  = m0 & 1023;
                union { bf16 h[4]; uint2 u; } t4;
                #pragma unroll
                for (int r = 0; r < 4; r++) t4.h[r] = f2b(acc[mt][nt][r] + bv);
                *(uint2*)&Cv[((size_t)(btok*H_ + hh)*D_ + dd)*S_ + key] = t4.u;
            }
        }
    }
}

// ============================================================================
// Output projection: m97-style 128x128 GEMM (unswapped, scalar-store
// epilogue). Unchanged.
// ============================================================================
__global__ __launch_bounds__(256) void oproj_gemm(
    const bf16* __restrict__ A, const bf16* __restrict__ W,
    const float* __restrict__ bias, float* __restrict__ C)
{
    const int K = E_, N = E_;
    const int bn = blockIdx.y * 128;
    const int bm = blockIdx.x * 128;

    __shared__ bf16 As[2][128][32];
    __shared__ bf16 Ws[2][128][32];

    const int tid  = threadIdx.x;
    const int lane = tid & 63;
    const int wv   = tid >> 6;
    const int wm   = (wv & 1) * 64;
    const int wn   = (wv >> 1) * 64;
    const int srow = wv * 16 + (lane >> 2);
    const int scol = (lane & 3) * 8;

    f32x4 acc[4][4] = {};

    for (int k0 = 0; k0 < K; k0 += 64) {
        __syncthreads();
        #pragma unroll
        for (int p = 0; p < 2; p++) {
            const int kc = k0 + p*32 + scol;
            gload_lds16(A + (size_t)(bm + srow)      * K + kc, &As[p][wv*16][0]);
            gload_lds16(A + (size_t)(bm + 64 + srow) * K + kc, &As[p][64 + wv*16][0]);
            gload_lds16(W + (size_t)(bn + srow)      * K + kc, &Ws[p][wv*16][0]);
            gload_lds16(W + (size_t)(bn + 64 + srow) * K + kc, &Ws[p][64 + wv*16][0]);
        }
        __syncthreads();

        const int fr = lane & 15;
        const int kq = (lane >> 4) * 8;
        #pragma unroll
        for (int p = 0; p < 2; p++) {
            bf16x8 af[4], wf[4];
            #pragma unroll
            for (int t = 0; t < 4; t++) {
                af[t] = *(const bf16x8*)&As[p][wm + t*16 + fr][kq];
                wf[t] = *(const bf16x8*)&Ws[p][wn + t*16 + fr][kq];
            }
            #pragma unroll
            for (int mt = 0; mt < 4; mt++)
                #pragma unroll
                for (int nt = 0; nt < 4; nt++)
                    acc[mt][nt] = __builtin_amdgcn_mfma_f32_16x16x32_bf16(
                        af[mt], wf[nt], acc[mt][nt], 0, 0, 0);
        }
    }

    const int col_l = lane & 15;
    const int row_l = (lane >> 4) * 4;
    #pragma unroll
    for (int nt = 0; nt < 4; nt++) {
        const int n = bn + wn + nt*16 + col_l;
        const float bv = bias[n];
        #pragma unroll
        for (int mt = 0; mt < 4; mt++) {
            #pragma unroll
            for (int r = 0; r < 4; r++) {
                const int m = bm + wm + mt*16 + row_l + r;
                C[(size_t)m * N + n] = acc[mt][nt][r] + bv;
            }
        }
    }
}

// ============================================================================
// MFMA flash attention v11d — unchanged. q/k arrive pre-roped, pre-scaled,
// in pair-interleaved D layout (QK^T permutation-invariant).
// ============================================================================
__global__ __launch_bounds__(512, 2) void attn_mfma(
    const bf16* __restrict__ q, const bf16* __restrict__ k, const bf16* __restrict__ vt,
    const int* __restrict__ cu, bf16* __restrict__ o)
{
    __shared__ __align__(16) bf16 Ks[2][64*80];    // 2 x 10240 B, swizzled
    __shared__ __align__(16) bf16 VTs[2][80*64];   // 2 x 10240 B, swizzled
    __shared__ __align__(16) bf16 PTq[8][16*72];   // per-wave P [query][key]

    const int n  = blockIdx.x;                 // 512 blocks
    const int g  = ((n >> 6) << 3) | (n & 7);  // (b,h): XCD = n&7 = h&7
    const int qs = (n >> 3) & 7;               // q-supertile 0..7 (128 rows)
    const int b  = g >> 4;
    const int h  = g & 15;

    const int tid  = threadIdx.x;
    const int lane = tid & 63, wv = tid >> 6;  // wv 0..7
    const int quad = lane >> 4, l15 = lane & 15;
    const int q0   = qs * 128;
    const int len  = cu[b + 1] - cu[b];

    const bool uniformq = (q0 >= len);
    const bool fast     = !uniformq && ((q0 + 128) <= len) && ((len & 63) == 0);
    const int  ktiles   = uniformq ? 16 : (fast ? (len >> 6) : 16);
    const bool domask   = !uniformq && !fast;

    bf16* PT = &PTq[wv][0];

    // Q fragments (B-operand), rows q0 + wv*16 + l15.
    bf16x8 qf[3] = {};
    if (!uniformq) {
        const bf16* qrow = q + (size_t)(b*S_ + q0 + wv*16 + l15)*E_ + h*D_ + quad*8;
        qf[0] = *(const bf16x8*)(qrow);
        qf[1] = *(const bf16x8*)(qrow + 32);
        if (quad < 2) qf[2] = *(const bf16x8*)(qrow + 64);
    }

    float m_s = -1e30f, l_s = 0.f;   // per-lane scalars (query = l15)
    f32x4 o_acc[5] = {};

    bf16x8 pone;
    {
        const short one_s = (short)0x3F80;   // bf16 1.0
        #pragma unroll
        for (int i = 0; i < 8; i++) pone[i] = one_s;
    }

    const int u_  = l15 >> 2;
    const int s0r = quad ^ u_;            // K granule ks=0
    const int sv0 = quad ^ (l15 & 7);     // V granule ks=0

    auto stage = [&](int kt, int bf) {
        #pragma unroll
        for (int i = 0; i < 3; i++) {
            int c = tid + i * 512;
            if (c < 640) {
                if (!uniformq) {
                    int row = c / 10, s5 = c - row * 10;
                    int uu = (row >> 2) & 3;
                    int sg = (s5 < 8) ? (s5 ^ uu) : (8 + ((s5 ^ uu) & 1));
                    gload_lds16(k + (size_t)(b*S_ + kt*64 + row)*E_ + h*D_ + sg*8,
                                &Ks[bf][c*8]);
                }
            } else if (c < 1280) {
                int c2 = c - 640;
                int row = c2 >> 3, s5 = c2 & 7;
                int sg = s5 ^ (row & 7);
                gload_lds16(vt + ((size_t)(b*H_ + h)*D_ + row)*S_ + kt*64 + sg*8,
                            &VTs[bf][c2*8]);
            }
        }
    };

    stage(0, 0);
    __syncthreads();   // buf0 ready

    for (int kt = 0; kt < ktiles; kt++) {
        const int cur = kt & 1;
        if (kt + 1 < ktiles) stage(kt + 1, cur ^ 1);   // loads fly during compute

        bf16x8 pf0 = pone, pf1 = pone;
        if (!uniformq) {
            // ---- QK^T swapped: A=K, B=Q -> C[key=quad*4+r (+nt*16)][query=l15]
            f32x4 s4[4];
            #pragma unroll
            for (int nt = 0; nt < 4; nt++) {
                const bf16* kr = &Ks[cur][(nt*16 + l15) * 80];
                bf16x8 kf0 = *(const bf16x8*)(kr + s0r*8);
                bf16x8 kf1 = *(const bf16x8*)(kr + 32 + s0r*8);
                bf16x8 kf2 = {};
                if (quad < 2) kf2 = *(const bf16x8*)(kr + 64 + (s0r & 1)*8);
                f32x4 a0 = {};
                a0 = __builtin_amdgcn_mfma_f32_16x16x32_bf16(kf0, qf[0], a0, 0, 0, 0);
                a0 = __builtin_amdgcn_mfma_f32_16x16x32_bf16(kf1, qf[1], a0, 0, 0, 0);
                a0 = __builtin_amdgcn_mfma_f32_16x16x32_bf16(kf2, qf[2], a0, 0, 0, 0);
                s4[nt] = a0;
            }

            // ---- masking (lane owns query l15; keys nt*16+quad*4+r)
            float sv[4][4];
            if (!domask) {
                #pragma unroll
                for (int nt = 0; nt < 4; nt++)
                    #pragma unroll
                    for (int r = 0; r < 4; r++)
                        sv[nt][r] = s4[nt][r];
            } else {
                const bool vq = (q0 + wv*16 + l15) < len;
                #pragma unroll
                for (int nt = 0; nt < 4; nt++)
                    #pragma unroll
                    for (int r = 0; r < 4; r++) {
                        const bool vk = (kt*64 + nt*16 + quad*4 + r) < len;
                        sv[nt][r] = (vq && vk) ? s4[nt][r] : -1e9f;
                    }
            }

            // ---- online softmax with T13 defer-max (THR=8)
            float rm[4];
            #pragma unroll
            for (int nt = 0; nt < 4; nt++)
                rm[nt] = fmaxf(fmaxf(sv[nt][0], sv[nt][1]), fmaxf(sv[nt][2], sv[nt][3]));
            float sloc = fmaxf(fmaxf(rm[0], rm[1]), fmaxf(rm[2], rm[3]));
            sloc = fmaxf(sloc, __shfl_xor(sloc, 16, 64));
            sloc = fmaxf(sloc, __shfl_xor(sloc, 32, 64));
            const bool resc = !__all(sloc <= m_s + 8.0f);   // wave-uniform
            const float mnew = resc ? fmaxf(m_s, sloc) : m_s;
            float p[4][4], lsum = 0.f;
            #pragma unroll
            for (int nt = 0; nt < 4; nt++)
                #pragma unroll
                for (int r = 0; r < 4; r++) {
                    p[nt][r] = __expf(sv[nt][r] - mnew);
                    lsum += p[nt][r];
                }
            lsum += __shfl_xor(lsum, 16, 64);
            lsum += __shfl_xor(lsum, 32, 64);
            if (resc) {
                const float alpha = __expf(m_s - mnew);
                l_s = l_s * alpha + lsum;
                m_s = mnew;
                #pragma unroll
                for (int dt = 0; dt < 5; dt++)
                    #pragma unroll
                    for (int r = 0; r < 4; r++)
                        o_acc[dt][r] *= alpha;
            } else {
                l_s += lsum;
            }

            // ---- P -> PT[query][key] (granule-swizzled, stride 72)
            #pragma unroll
            for (int nt = 0; nt < 4; nt++) {
                union { bf16 hh[4]; uint2 u; } w;
                #pragma unroll
                for (int r = 0; r < 4; r++) w.hh[r] = f2b(p[nt][r]);
                const int gw = (2*nt + (quad >> 1)) ^ (l15 & 7);
                *(uint2*)&PT[l15*72 + gw*8 + (quad & 1)*4] = w.u;
            }
            // ---- P-frags (same-wave RAW via lgkmcnt)
            pf0 = *(const bf16x8*)&PT[l15*72 + ((quad    ) ^ (l15 & 7))*8];
            pf1 = *(const bf16x8*)&PT[l15*72 + ((quad + 4) ^ (l15 & 7))*8];
        }

        // ---- PV: A=Vfrag, B=Pfrag -> O[d=quad*4+r (+dt*16)][query=l15]
        #pragma unroll
        for (int dt = 0; dt < 5; dt++) {
            const bf16* vr = &VTs[cur][(dt*16 + l15) * 64];
            bf16x8 vf0 = *(const bf16x8*)(vr + sv0*8);
            bf16x8 vf1 = *(const bf16x8*)(vr + (sv0 ^ 4)*8);
            o_acc[dt] = __builtin_amdgcn_mfma_f32_16x16x32_bf16(vf0, pf0, o_acc[dt], 0, 0, 0);
            o_acc[dt] = __builtin_amdgcn_mfma_f32_16x16x32_bf16(vf1, pf1, o_acc[dt], 0, 0, 0);
        }
        __syncthreads();   // reads of buf[cur] done; buf[cur^1] loads drained
    }

    // ---- epilogue: lane = query l15; d = dt*16 + quad*4 + r
    const float inv = uniformq ? (1.0f / 1024.0f) : (1.0f / l_s);
    const size_t row_g = (size_t)(b*S_ + q0 + wv*16 + l15);
    #pragma unroll
    for (int dt = 0; dt < 5; dt++) {
        union { bf16 hh[4]; uint2 u; } t4;
        #pragma unroll
        for (int r = 0; r < 4; r++) t4.hh[r] = f2b(o_acc[dt][r] * inv);
        *(uint2*)&o[row_g*E_ + h*D_ + dt*16 + quad*4] = t4.u;
    }
}

extern "C" void kernel_launch(void* const* d_in, const int* in_sizes, int n_in,
                              void* d_out, int out_size, void* d_ws, size_t ws_size,
                              hipStream_t stream)
{
    const float* x    = (const float*)d_in[0];
    const int*   cu   = (const int*)  d_in[1];
    const float* cosp = (const float*)d_in[2];
    const float* sinp = (const float*)d_in[3];
    const float* wq   = (const float*)d_in[4];
    const float* bq   = (const float*)d_in[5];
    const float* wk   = (const float*)d_in[6];
    const float* bk   = (const float*)d_in[7];
    const float* wv   = (const float*)d_in[8];
    const float* bv   = (const float*)d_in[9];
    const float* wo   = (const float*)d_in[10];
    const float* bo   = (const float*)d_in[11];
    float* out = (float*)d_out;

    bf16* q   = (bf16*)d_ws;
    bf16* kk  = q   + (size_t)M_ * E_;
    bf16* vt  = kk  + (size_t)M_ * E_;   // transposed V: [B][H][D][S]
    bf16* ao  = vt  + (size_t)M_ * E_;
    bf16* xb  = ao  + (size_t)M_ * E_;
    bf16* wqb = xb  + (size_t)M_ * E_;
    bf16* wkb = wqb + (size_t)E_ * E_;
    bf16* wvb = wkb + (size_t)E_ * E_;
    bf16* wob = wvb + (size_t)E_ * E_;
    float* cst = (float*)(wob + (size_t)E_ * E_);   // 40*1024*2 f32 = 320 KB

    // 0) convert x + 4 weight matrices to bf16 (wq/wk pair-interleaved),
    //    + build the fused transposed rope table cst (slice y=5)
    cvt_kernel<<<dim3(2560, 6), 256, 0, stream>>>(
        x, wq, wk, wv, wo, cosp, sinp, xb, wqb, wkb, wvb, wob, cst, M_*E_, E_*E_);

    // 1) QKV projection with FUSED RoPE (q pre-scaled), vectorized cs loads.
    qkv_gemm_8ph<<<dim3(M_/256, 15), 512, 0, stream>>>(
        xb, wqb, wkb, wvb, bq, bk, bv, cst, q, kk, vt);

    // 2) MFMA flash attention v11d
    attn_mfma<<<512, 512, 0, stream>>>(q, kk, vt, cu, ao);

    // 3) output projection (m97 GEMM, fp32 out, bias fused)
    oproj_gemm<<<dim3(M_/128, E_/128), 256, 0, stream>>>(ao, wob, bo, out);
}